// Round 2
// baseline (353.891 us; speedup 1.0000x reference)
//
#include <hip/hip_runtime.h>
#include <hip/hip_fp16.h>

// Q4_0-style dequant, harness delivers raw_data as one int32 PER BYTE.
// Block b occupies raw32[b*18 .. b*18+17]:
//   ints 0,1   : low bytes of the fp16 scale (little-endian)
//   ints 2..17 : the 16 packed quant bytes
// out[b*32 + j]      = scale * ((byte_j & 15) - 8)   j in [0,16)
// out[b*32 + 16 + j] = scale * ((byte_j >> 4) - 8)
//
// v2b: identical to v2 (128 quant blocks / WG, 4 independent chains per
// thread, nontemporal streaming loads+stores) plus explicit 16-B alignment
// on the LDS array for the int4 staging casts. Round-1 failure was an
// infra/container error, not a kernel verdict.

typedef int   i4 __attribute__((ext_vector_type(4)));
typedef int   i2 __attribute__((ext_vector_type(2)));
typedef float f4 __attribute__((ext_vector_type(4)));

constexpr long long NUMEL = 8192LL * 8192LL;
constexpr int QK = 32;
constexpr long long NBLOCKS = NUMEL / QK;        // 2,097,152
constexpr int BLOCK_INTS = 18;                   // int32 elements per quant block
constexpr int WG_BLOCKS = 128;                   // quant blocks per workgroup
constexpr int WG_INTS = WG_BLOCKS * BLOCK_INTS;  // 2304 ints = 9216 B
constexpr int WG_INT4 = WG_INTS / 4;             // 576

__global__ __launch_bounds__(256)
void dequant_q4_kernel(const int* __restrict__ raw32,
                       f4* __restrict__ out4)
{
    __shared__ __align__(16) int lds[WG_INTS];

    const int tid = threadIdx.x;
    const long long wg = blockIdx.x;

    // ---- stage 9216 B of input, fully coalesced, nontemporal ----
    const i4* __restrict__ src = (const i4*)(raw32 + wg * (long long)WG_INTS);
    i4* lds4 = (i4*)lds;

    lds4[tid]       = __builtin_nontemporal_load(src + tid);
    lds4[tid + 256] = __builtin_nontemporal_load(src + tid + 256);
    if (tid < WG_INT4 - 512)                      // 64 threads
        lds4[tid + 512] = __builtin_nontemporal_load(src + tid + 512);

    __syncthreads();

    // ---- dequant: 4 independent chains per thread ----
    const int k  = tid & 7;                      // sub-slot within a block
    const int j  = (k & 3) * 4;
    const int sh = (k >= 4) ? 4 : 0;             // low vs high nibble
    const int c  = tid >> 3;                     // local quant block 0..31
    const long long outbase = wg * (long long)(WG_BLOCKS * 8) + tid;

#pragma unroll
    for (int r = 0; r < 4; ++r) {
        const int base = (c + r * 32) * BLOCK_INTS;

        // fp16 scale from low bytes of ints 0,1 (8-aligned)
        const i2 s = *(const i2*)(lds + base);
        const unsigned short s16 =
            (unsigned short)((s.x & 0xff) | ((s.y & 0xff) << 8));
        const float scale = __half2float(__ushort_as_half(s16));

        // 4 quant bytes for this slot = 4 consecutive ints, two i2 reads
        const i2 q01 = *(const i2*)(lds + base + 2 + j);
        const i2 q23 = *(const i2*)(lds + base + 4 + j);

        f4 o;
        o.x = scale * (float)(((q01.x >> sh) & 15) - 8);
        o.y = scale * (float)(((q01.y >> sh) & 15) - 8);
        o.z = scale * (float)(((q23.x >> sh) & 15) - 8);
        o.w = scale * (float)(((q23.y >> sh) & 15) - 8);

        __builtin_nontemporal_store(o, out4 + outbase + r * 256);
    }
}

extern "C" void kernel_launch(void* const* d_in, const int* in_sizes, int n_in,
                              void* d_out, int out_size, void* d_ws, size_t ws_size,
                              hipStream_t stream)
{
    const int* raw32 = (const int*)d_in[0];
    f4* out4 = (f4*)d_out;

    const long long n_wg = NBLOCKS / WG_BLOCKS;   // 16,384 workgroups
    dequant_q4_kernel<<<dim3((unsigned)n_wg), dim3(256), 0, stream>>>(raw32, out4);
}